// Round 5
// baseline (195.670 us; speedup 1.0000x reference)
//
#include <hip/hip_runtime.h>

// Problem constants (from reference)
#define NCH   1024
#define CBLK  8
#define MOUT  128   // NCH / CBLK
#define BSZ   16
#define TLEN  2048

// Fused kernel:
//  - grid = BSZ*MOUT = 2048 blocks, 256 threads each
//  - each block computes one Ax row: Ax[b][m][t] = sum_c tanh(blocks[m*8+c]) * x[b][m*8+c][t]
//  - additionally, each block's lanes 0..63 write 64 elements of A_full
//    (A_full[i][j] = (i == j/8) ? tanh(blocks[j]) : 0 ; 2048 blocks * 64 = 131072)
__global__ __launch_bounds__(256)
void fused_kernel(const float* __restrict__ x,
                  const float* __restrict__ blocks,
                  float* __restrict__ ax,
                  float* __restrict__ afull) {
    const int bm = blockIdx.x;          // 0 .. B*MOUT-1
    const int m  = bm & (MOUT - 1);
    const int b  = bm >> 7;             // MOUT = 128 = 2^7

    // A_full slice: 64 elements per block
    if (threadIdx.x < 64) {
        const int idx = bm * 64 + threadIdx.x;   // 0 .. 131071
        const int i = idx >> 10;                 // row 0..127
        const int j = idx & 1023;                // col 0..1023
        float v = 0.0f;
        if ((j >> 3) == i) v = tanhf(blocks[j]);
        afull[idx] = v;
    }

    __shared__ float w[CBLK];
    if (threadIdx.x < CBLK) w[threadIdx.x] = tanhf(blocks[m * CBLK + threadIdx.x]);
    __syncthreads();

    const float*  xb = x  + ((size_t)b * NCH  + (size_t)m * CBLK) * TLEN;
    float*        ob = ax + ((size_t)b * MOUT + (size_t)m) * TLEN;
    const float4* x4 = reinterpret_cast<const float4*>(xb);
    float4*       o4 = reinterpret_cast<float4*>(ob);

    // 2048 floats = 512 float4 per output row; 256 threads -> 2 each
    #pragma unroll
    for (int r = 0; r < 2; ++r) {
        const int t4 = threadIdx.x + r * 256;
        float4 acc = make_float4(0.f, 0.f, 0.f, 0.f);
        #pragma unroll
        for (int c = 0; c < CBLK; ++c) {
            float4 v = x4[(size_t)c * (TLEN / 4) + t4];
            const float wc = w[c];
            acc.x = fmaf(v.x, wc, acc.x);
            acc.y = fmaf(v.y, wc, acc.y);
            acc.z = fmaf(v.z, wc, acc.z);
            acc.w = fmaf(v.w, wc, acc.w);
        }
        o4[t4] = acc;
    }
}

extern "C" void kernel_launch(void* const* d_in, const int* in_sizes, int n_in,
                              void* d_out, int out_size, void* d_ws, size_t ws_size,
                              hipStream_t stream) {
    const float* x      = (const float*)d_in[0];   // (16,1,1024,2048) f32
    const float* blocks = (const float*)d_in[1];   // (128,8) f32

    float* ax    = (float*)d_out;                              // 16*128*2048
    float* afull = (float*)d_out + (size_t)BSZ * MOUT * TLEN;  // 128*1024

    fused_kernel<<<BSZ * MOUT, 256, 0, stream>>>(x, blocks, ax, afull);
}

// Round 9
// 183.970 us; speedup vs baseline: 1.0636x; 1.0636x over previous
//
#include <hip/hip_runtime.h>

// Problem constants (from reference)
#define NCH   1024
#define CBLK  8
#define MOUT  128   // NCH / CBLK
#define BSZ   16
#define TLEN  2048

// Native clang vector type so __builtin_nontemporal_* accepts it
typedef float floatx4 __attribute__((ext_vector_type(4)));

// Fused kernel:
//  - grid = BSZ*MOUT = 2048 blocks (8 wg/CU), 256 threads
//  - each block computes one Ax row: Ax[b][m][t] = sum_c tanh(blocks[m*8+c]) * x[b][m*8+c][t]
//  - each block's lanes 0..63 also write 64 elements of A_full
//    (A_full[i][j] = (i == j/8) ? tanh(blocks[j]) : 0 ; 2048 blocks * 64 = 131072)
//  - x streamed once (NT loads), outputs never re-read (NT stores)
__global__ __launch_bounds__(256)
void fused_kernel(const float* __restrict__ x,
                  const float* __restrict__ blocks,
                  float* __restrict__ ax,
                  float* __restrict__ afull) {
    const int bm = blockIdx.x;          // 0 .. B*MOUT-1
    const int m  = bm & (MOUT - 1);
    const int b  = bm >> 7;             // MOUT = 128 = 2^7

    // A_full slice: 64 elements per block
    if (threadIdx.x < 64) {
        const int idx = bm * 64 + threadIdx.x;   // 0 .. 131071
        const int i = idx >> 10;                 // row 0..127
        const int j = idx & 1023;                // col 0..1023
        float v = 0.0f;
        if ((j >> 3) == i) v = tanhf(blocks[j]);
        __builtin_nontemporal_store(v, &afull[idx]);
    }

    __shared__ float w[CBLK];
    if (threadIdx.x < CBLK) w[threadIdx.x] = tanhf(blocks[m * CBLK + threadIdx.x]);
    __syncthreads();

    const float*   xb = x  + ((size_t)b * NCH  + (size_t)m * CBLK) * TLEN;
    float*         ob = ax + ((size_t)b * MOUT + (size_t)m) * TLEN;
    const floatx4* x4 = reinterpret_cast<const floatx4*>(xb);
    floatx4*       o4 = reinterpret_cast<floatx4*>(ob);

    // 2048 floats = 512 float4 per output row; 256 threads -> 2 each
    #pragma unroll
    for (int r = 0; r < 2; ++r) {
        const int t4 = threadIdx.x + r * 256;
        floatx4 acc = (floatx4)(0.0f);
        #pragma unroll
        for (int c = 0; c < CBLK; ++c) {
            floatx4 v = __builtin_nontemporal_load(&x4[(size_t)c * (TLEN / 4) + t4]);
            const float wc = w[c];
            acc.x = fmaf(v.x, wc, acc.x);
            acc.y = fmaf(v.y, wc, acc.y);
            acc.z = fmaf(v.z, wc, acc.z);
            acc.w = fmaf(v.w, wc, acc.w);
        }
        __builtin_nontemporal_store(acc, &o4[t4]);
    }
}

extern "C" void kernel_launch(void* const* d_in, const int* in_sizes, int n_in,
                              void* d_out, int out_size, void* d_ws, size_t ws_size,
                              hipStream_t stream) {
    const float* x      = (const float*)d_in[0];   // (16,1,1024,2048) f32
    const float* blocks = (const float*)d_in[1];   // (128,8) f32

    float* ax    = (float*)d_out;                              // 16*128*2048
    float* afull = (float*)d_out + (size_t)BSZ * MOUT * TLEN;  // 128*1024

    fused_kernel<<<BSZ * MOUT, 256, 0, stream>>>(x, blocks, ax, afull);
}